// Round 14
// baseline (99.380 us; speedup 1.0000x reference)
//
#include <hip/hip_runtime.h>

// Problem constants
#define BATCH 4
#define SEQ   2048
#define INC   512
#define NH    8
#define OUTC  64      // space dim; head dim = 65
#define DD    65
#define NROW  (BATCH * NH * SEQ)   // 65536
#define PSTRIDE 72    // partial row stride in us units (144 B)

typedef float f32x4 __attribute__((ext_vector_type(4)));
typedef short short8 __attribute__((ext_vector_type(8)));
typedef short short4v __attribute__((ext_vector_type(4)));
typedef unsigned int uint2v __attribute__((ext_vector_type(2)));
typedef unsigned short us;

static __device__ __forceinline__ us f2b(float f) {
  unsigned int u = __float_as_uint(f);
  u = (u + 0x7FFFu + ((u >> 16) & 1u)) >> 16;   // RNE f32->bf16
  return (us)u;
}
static __device__ __forceinline__ float b2f(us h) {
  return __uint_as_float(((unsigned int)h) << 16);
}
static __device__ __forceinline__ unsigned int pk2(float lo, float hi) {
  unsigned int r;
  asm("v_cvt_pk_bf16_f32 %0, %1, %2" : "=v"(r) : "v"(lo), "v"(hi));
  return r;
}
static __device__ __forceinline__ short8 mk8(unsigned int a, unsigned int b,
                                             unsigned int c, unsigned int d) {
  union { unsigned int u[4]; short8 s; } x;
  x.u[0] = a; x.u[1] = b; x.u[2] = c; x.u[3] = d;
  return x.s;
}

#define GLDS(g, l) __builtin_amdgcn_global_load_lds( \
    (const __attribute__((address_space(1))) void*)(g), \
    (__attribute__((address_space(3))) void*)(l), 16, 0, 0)
#define SB() __builtin_amdgcn_sched_barrier(0)

// ---------------------------------------------------------------------------
// Kernel 0: f32 -> bf16 for the THREE W matrices only (X converts inline in
// proj now). 0.5 MB each.
// ---------------------------------------------------------------------------
__global__ __launch_bounds__(256) void tobf16_kernel(
    const float* __restrict__ Wq, const float* __restrict__ Wk,
    const float* __restrict__ Wv,
    us* __restrict__ dWq, us* __restrict__ dWk, us* __restrict__ dWv)
{
  const int which = blockIdx.y;
  const float* src = (which == 0) ? Wq : (which == 1 ? Wk : Wv);
  us* dst = (which == 0) ? dWq : (which == 1 ? dWk : dWv);
  const int n = NH * OUTC * INC;
  for (long i = (long)blockIdx.x * 256 + threadIdx.x; i * 4 < n;
       i += (long)gridDim.x * 256) {
    f32x4 v = *(const f32x4*)(src + i * 4);
    short4v o;
    o[0] = (short)f2b(v[0]); o[1] = (short)f2b(v[1]);
    o[2] = (short)f2b(v[2]); o[3] = (short)f2b(v[3]);
    *(short4v*)(dst + i * 4) = o;
  }
}

// ---------------------------------------------------------------------------
// Kernel 1: per-head projections. X read DIRECTLY as f32, converted in
// registers (cvt_pk, RNE) while staging into the swizzled LDS layout;
// W stays bf16 + GLDS. 1-deep prefetch, ONE barrier per K-step:
//   iter t: [issue Wg_{t+1}(GLDS) + Xl_{t+1}(f32 regs)] -> MFMA(buf_t) ->
//           vmcnt(0) -> convert+ds_write(buf_{t+1}) -> lgkmcnt(0) -> barrier
// Buffer-reuse safety: write to buf_{t+1} is ordered after all reads of it
// (iter t-1) by the end-of-(t-1) barrier.
//   Q: space pre-scaled by al2; qta u32 = (qh|ql<<16) of al2*t.
//   K: kta u32 = (-kh)|(-kl)<<16.   V: transposed epilogue -> vT [B,H,64,S].
// ---------------------------------------------------------------------------
__global__ __launch_bounds__(256) void proj_kernel(
    const float* __restrict__ Xq, const float* __restrict__ Xs,
    const us* __restrict__ Wqb, const us* __restrict__ Wkb, const us* __restrict__ Wvb,
    const float* __restrict__ Bq, const float* __restrict__ Bk, const float* __restrict__ Bv,
    const float* __restrict__ scale_p,
    us* __restrict__ qs, unsigned int* __restrict__ qta,
    us* __restrict__ ks, unsigned int* __restrict__ kta,
    us* __restrict__ vT, us* __restrict__ vtc)
{
  const int which = blockIdx.z;
  const float* Xf = (which == 0) ? Xq : Xs;
  const us* W = (which == 0) ? Wqb : (which == 1 ? Wkb : Wvb);
  const float* Bb = (which == 0) ? Bq : (which == 1 ? Bk : Bv);
  const float al2 = (2.0f / scale_p[0]) * 1.44269504088896f;
  const float oscale = (which == 0) ? al2 : 1.0f;

  const int lin = blockIdx.x;                    // 0..1023
  const int h   = (lin >> 3) & 7;
  const int m0  = (((lin >> 6) << 3) | (lin & 7)) * 64;
  const int n0  = h * 64;

  __shared__ alignas(16) us lXf[2 * 64 * 64];
  __shared__ alignas(16) us lWf[2 * 64 * 64];

  const int tid  = threadIdx.x;
  const int lane = tid & 63;
  const int wave = tid >> 6;
  const int arow = lane & 15;
  const int agrp = lane >> 4;
  const int rl   = lane >> 3;
  const int chx  = ((lane & 7) ^ rl) * 8;
  const int r0   = wave * 8 + rl;
  const int r1   = r0 + 32;
  // X staging geometry (reg path): 2 units/thread cover 64 rows x 8 chunks
  const int xrow  = tid >> 3;        // 0..31 (unit1: +32)
  const int xch   = tid & 7;
  const int xslot = xch ^ (xrow & 7);

#define WSTAGE(buf, k0) do { \
    GLDS(W + (size_t)(n0 + r0) * INC + (k0) + chx, &lWf[(buf) * 4096 + wave * 512]); \
    GLDS(W + (size_t)(n0 + r1) * INC + (k0) + chx, &lWf[(buf) * 4096 + 2048 + wave * 512]); \
  } while (0)

  f32x4 xa0, xb0, xa1, xb1;
#define XLOAD(k0) do { \
    const float* xb = Xf + (size_t)(m0 + xrow) * INC + (k0) + xch * 8; \
    xa0 = *(const f32x4*)xb;              xb0 = *(const f32x4*)(xb + 4); \
    xa1 = *(const f32x4*)(xb + 32 * INC); xb1 = *(const f32x4*)(xb + 32 * INC + 4); \
  } while (0)
#define XWRITE(buf) do { \
    *(short8*)&lXf[(buf) * 4096 + xrow * 64 + xslot * 8] = \
        mk8(pk2(xa0[0], xa0[1]), pk2(xa0[2], xa0[3]), \
            pk2(xb0[0], xb0[1]), pk2(xb0[2], xb0[3])); \
    *(short8*)&lXf[(buf) * 4096 + 2048 + xrow * 64 + xslot * 8] = \
        mk8(pk2(xa1[0], xa1[1]), pk2(xa1[2], xa1[3]), \
            pk2(xb1[0], xb1[1]), pk2(xb1[2], xb1[3])); \
  } while (0)

  f32x4 acc[4] = {};

  // prologue: stage tile 0
  XLOAD(0);
  WSTAGE(0, 0);
  SB();
  asm volatile("s_waitcnt vmcnt(0)");
  XWRITE(0);
  asm volatile("s_waitcnt lgkmcnt(0)");
  SB();
  __builtin_amdgcn_s_barrier();

  for (int kk = 0; kk < 8; ++kk) {
    const int cur = kk & 1;
    if (kk < 7) {
      WSTAGE(cur ^ 1, (kk + 1) * 64);
      XLOAD((kk + 1) * 64);
    }
    SB();
#pragma unroll
    for (int kc = 0; kc < 2; ++kc) {
      short8 af = *(const short8*)&lXf[cur * 4096 + (wave * 16 + arow) * 64 + (((kc * 4 + agrp) ^ (arow & 7)) * 8)];
#pragma unroll
      for (int c = 0; c < 4; ++c) {
        short8 bf = *(const short8*)&lWf[cur * 4096 + (c * 16 + arow) * 64 + (((kc * 4 + agrp) ^ (arow & 7)) * 8)];
        acc[c] = __builtin_amdgcn_mfma_f32_16x16x32_bf16(af, bf, acc[c], 0, 0, 0);
      }
    }
    SB();
    if (kk < 7) {
      asm volatile("s_waitcnt vmcnt(0)");
      XWRITE(cur ^ 1);
      asm volatile("s_waitcnt lgkmcnt(0)");
      SB();
      __builtin_amdgcn_s_barrier();
    }
  }
  __syncthreads();   // all MFMAs done -> lXf fully reusable (lT spans both bufs)

  float bcol[4];
#pragma unroll
  for (int c = 0; c < 4; ++c) bcol[c] = Bb[n0 + c * 16 + arow];

  us* lT = &lXf[0];   // 64 x 72 us transpose tile (V path only)

#pragma unroll
  for (int r = 0; r < 4; ++r) {
    float s2 = 0.f;
#pragma unroll
    for (int c = 0; c < 4; ++c) {
      float v = acc[c][r] + bcol[c];
      acc[c][r] = v;
      s2 += v * v;
    }
    s2 += __shfl_xor(s2, 1); s2 += __shfl_xor(s2, 2);
    s2 += __shfl_xor(s2, 4); s2 += __shfl_xor(s2, 8);
    float tv = sqrtf(s2 + 1.0f);
    int gs = m0 + wave * 16 + agrp * 4 + r;
    int bi = gs >> 11, si = gs & (SEQ - 1);
    size_t rowbase = (size_t)(bi * NH + h) * SEQ + si;
    if (which == 2) {
      int lrow = wave * 16 + agrp * 4 + r;
#pragma unroll
      for (int c = 0; c < 4; ++c)
        lT[lrow * PSTRIDE + c * 16 + arow] = f2b(acc[c][r]);
      if (arow == 0) {
        us th = f2b(tv);
        us tl = f2b(tv - b2f(th));
        vtc[rowbase] = th;
        vtc[NROW + rowbase] = tl;
      }
    } else {
      us* outs = (which == 0) ? qs : ks;
      size_t obase = rowbase * 64;
#pragma unroll
      for (int c = 0; c < 4; ++c) outs[obase + c * 16 + arow] = f2b(oscale * acc[c][r]);
      if (arow == 0) {
        if (which == 0) {
          float st = al2 * tv;
          us qh = f2b(st);
          us ql = f2b(st - b2f(qh));
          qta[rowbase] = (unsigned int)qh | ((unsigned int)ql << 16);
        } else {
          kta[rowbase] = (unsigned int)(us)(f2b(tv) ^ 0x8000)
                       | ((unsigned int)(us)(f2b(tv - b2f(f2b(tv))) ^ 0x8000) << 16);
        }
      }
    }
  }

  if (which == 2) {
    __syncthreads();
    const int bi = m0 >> 11, si0 = m0 & (SEQ - 1);
    us* vbase = vT + ((size_t)(bi * NH + h) * 64) * SEQ + si0;
#pragma unroll
    for (int u0 = 0; u0 < 2; ++u0) {
      int u = tid + u0 * 256;
      int o = u >> 3, jc = u & 7;
      short8 w;
#pragma unroll
      for (int j = 0; j < 8; ++j) w[j] = (short)lT[(jc * 8 + j) * PSTRIDE + o];
      *(short8*)(vbase + (size_t)o * SEQ + jc * 8) = w;
    }
  }
}

// ---------------------------------------------------------------------------
// Kernel 3: causal flash attention (R12/R13 structure, unchanged): 8-wave
// blocks (512 thr), QBLK=128, KBLK=64, grid 768 = 32 bh x 8 pairs {x,15-x}
// x 3-way split of the pair's 36 k-tiles. Partials 144 B/row.
// ---------------------------------------------------------------------------
__global__ __launch_bounds__(512) void attn_kernel(
    const us* __restrict__ qs, const unsigned int* __restrict__ qta,
    const us* __restrict__ ks, const unsigned int* __restrict__ kta,
    const us* __restrict__ vT, const us* __restrict__ vtc,
    us* __restrict__ part)
{
  // XCD-aware swizzle: the 24 blocks of one bh land on one XCD.
  const int f = blockIdx.x;              // 768 blocks
  const int xcd = f & 7, idx = f >> 3;   // idx in [0,96)
  const int bh = xcd * 4 + (idx / 24);
  const int inner = idx % 24;
  const int x = inner / 3;               // pair {x, 15-x}
  const int s = inner % 3;               // 3-way split slot
  const int n0 = 2 * x + 2;
  const int n1 = 32 - 2 * x;

  __shared__ alignas(16) us lK[2][64 * 64];
  __shared__ alignas(16) us lV[2][64 * 64];
  __shared__ alignas(16) us lP[8][16 * 40];

  const int tid  = threadIdx.x;
  const int lane = tid & 63;
  const int wave = tid >> 6;     // 0..7
  const int arow = lane & 15;
  const int agrp = lane >> 4;

  const size_t bhbase = (size_t)bh * SEQ;
  const us* kgp = ks + bhbase * 64;
  const us* vgp = vT + (size_t)bh * 64 * SEQ;
  const unsigned int* ktp = kta + bhbase;
  const us* vtp = vtc + (size_t)(arow & 1) * NROW + bhbase;

  const int rl   = lane >> 3;
  const int chx  = ((lane & 7) ^ rl) * 8;
  const int dsl0 = (agrp ^ (arow & 7)) * 8;
  const int dsl1 = ((4 + agrp) ^ (arow & 7)) * 8;
  us* myP = &lP[wave][0];
  const int pw0 = arow * 40 + agrp * 4;   // P b64 write (c=1: +16)
  const int prd = arow * 40 + agrp * 8;   // pf b128 read

#define ASTAGE(buf, t64) do { \
    const int kk = (t64) * 64; \
    GLDS(kgp + (size_t)(kk + wave * 8 + rl) * 64 + chx, &lK[buf][wave * 512]); \
    GLDS(vgp + (size_t)(wave * 8 + rl) * SEQ + kk + chx, &lV[buf][wave * 512]); \
  } while (0)

  short8 ones8, zero8 = {};
#pragma unroll
  for (int j = 0; j < 8; ++j) ones8[j] = (short)0x3F80;

  for (int seg = 0; seg < 2; ++seg) {
    const int qT = seg ? (15 - x) : x;
    int lo, hi;
    if (seg == 0) { lo = min(12 * s, n0);          hi = min(12 * s + 12, n0); }
    else          { lo = max(12 * s - n0, 0);      hi = min(12 * s + 12 - n0, n1); }
    const int nt = hi - lo;
    if (nt <= 0) continue;

    const int wq = qT * 128 + wave * 16 + arow;
    f32x4 acc[5] = {};

    // Q fragments + time terms (3 VMEM)
    const us* qp = qs + (bhbase + wq) * 64;
    short8 qf0 = *(const short8*)(qp + agrp * 8);
    short8 qf1 = *(const short8*)(qp + 32 + agrp * 8);
    unsigned int qw = qta[bhbase + wq];
    short8 qf2 = {};
    if (agrp == 0) {
      qf2[0] = (short)(qw & 0xFFFFu);
      qf2[1] = (short)(qw & 0xFFFFu);
      qf2[2] = (short)(qw >> 16);
    }

    // aug regs for first tile (4 + 2 = 6 VMEM)
    unsigned int ka[4];
    short8 va0, va1;
    {
      const int kk = lo * 64;
#pragma unroll
      for (int c = 0; c < 4; ++c) ka[c] = ktp[kk + c * 16 + arow];
      va0 = *(const short8*)(vtp + kk + agrp * 8);
      va1 = *(const short8*)(vtp + kk + 32 + agrp * 8);
    }
    SB();
    ASTAGE(0, lo);
    SB();

    for (int it = 0; it < nt; ++it) {
      const int t = lo + it;
      const int cur = it & 1;
      if (it < nt - 1) {
        ASTAGE(cur ^ 1, t + 1);
        SB();
        asm volatile("s_waitcnt vmcnt(2)");
      } else {
        SB();
        asm volatile("s_waitcnt vmcnt(0)");
      }
      SB();
      __builtin_amdgcn_s_barrier();

      const us* Kb = lK[cur];
      const us* Vb = lV[cur];

      // ---- S^T = K' Q'^T (augmented: includes -qt*kt hi/lo) ----
      f32x4 sS[4] = {};
      __builtin_amdgcn_s_setprio(1);
#pragma unroll
      for (int c = 0; c < 4; ++c) {
        short8 kf = *(const short8*)&Kb[(c * 16 + arow) * 64 + dsl0];
        sS[c] = __builtin_amdgcn_mfma_f32_16x16x32_bf16(kf, qf0, sS[c], 0, 0, 0);
      }
#pragma unroll
      for (int c = 0; c < 4; ++c) {
        short8 kf = *(const short8*)&Kb[(c * 16 + arow) * 64 + dsl1];
        sS[c] = __builtin_amdgcn_mfma_f32_16x16x32_bf16(kf, qf1, sS[c], 0, 0, 0);
      }
#pragma unroll
      for (int c = 0; c < 4; ++c) {
        short8 kf2 = {};
        if (agrp == 0) {
          unsigned int w0 = ka[c];
          kf2[0] = (short)(w0 & 0xFFFFu);
          kf2[1] = (short)(w0 >> 16);
          kf2[2] = (short)(w0 & 0xFFFFu);
        }
        sS[c] = __builtin_amdgcn_mfma_f32_16x16x32_bf16(kf2, qf2, sS[c], 0, 0, 0);
      }
      __builtin_amdgcn_s_setprio(0);

      // ---- P = exp2(logit) (Q pre-scaled); causal mask -> exact 0 ----
#pragma unroll
      for (int c = 0; c < 4; ++c)
#pragma unroll
        for (int r = 0; r < 4; ++r)
          sS[c][r] = exp2f(sS[c][r]);
      if (t >= 2 * qT) {     // the two diagonal-straddling k-tiles
        const int kb = t * 64;
#pragma unroll
        for (int c = 0; c < 4; ++c)
#pragma unroll
          for (int r = 0; r < 4; ++r)
            if (kb + c * 16 + agrp * 4 + r > wq) sS[c][r] = 0.f;
      }

      // ---- PV: 2 phases over kc, wave-private 1.25KB P tile reused ----
      {
        uint2v w;
        w[0] = pk2(sS[0][0], sS[0][1]); w[1] = pk2(sS[0][2], sS[0][3]);
        *(uint2v*)&myP[pw0] = w;
        w[0] = pk2(sS[1][0], sS[1][1]); w[1] = pk2(sS[1][2], sS[1][3]);
        *(uint2v*)&myP[pw0 + 16] = w;
        short8 pf = *(const short8*)&myP[prd];
        __builtin_amdgcn_s_setprio(1);
#pragma unroll
        for (int dc = 0; dc < 4; ++dc) {
          short8 vf = *(const short8*)&Vb[(dc * 16 + arow) * 64 + dsl0];
          acc[dc] = __builtin_amdgcn_mfma_f32_16x16x32_bf16(pf, vf, acc[dc], 0, 0, 0);
        }
        short8 vf4 = (arow < 2) ? va0 : ((arow == 2) ? ones8 : zero8);
        acc[4] = __builtin_amdgcn_mfma_f32_16x16x32_bf16(pf, vf4, acc[4], 0, 0, 0);
        __builtin_amdgcn_s_setprio(0);
      }
      {
        uint2v w;
        w[0] = pk2(sS[2][0], sS[2][1]); w[1] = pk2(sS[2][2], sS[2][3]);
        *(uint2v*)&myP[pw0] = w;
        w[0] = pk2(sS[3][0], sS[3][1]); w[1] = pk2(sS[3][2], sS[3][3]);
        *(uint2v*)&myP[pw0 + 16] = w;
        short8 pf = *(const short8*)&myP[prd];
        __builtin_amdgcn_s_setprio(1);
#pragma unroll
        for (int dc = 0; dc < 4; ++dc) {
          short8 vf = *(const short8*)&Vb[(dc * 16 + arow) * 64 + dsl1];
          acc[dc] = __builtin_amdgcn_mfma_f32_16x16x32_bf16(pf, vf, acc[dc], 0, 0, 0);
        }
        short8 vf4 = (arow < 2) ? va1 : ((arow == 2) ? ones8 : zero8);
        acc[4] = __builtin_amdgcn_mfma_f32_16x16x32_bf16(pf, vf4, acc[4], 0, 0, 0);
        __builtin_amdgcn_s_setprio(0);
      }

      // aug prefetch for next tile (in flight across the barrier)
      SB();
      if (it + 1 < nt) {
        const int kk = (t + 1) * 64;
#pragma unroll
        for (int c = 0; c < 4; ++c) ka[c] = ktp[kk + c * 16 + arow];
        va0 = *(const short8*)(vtp + kk + agrp * 8);
        va1 = *(const short8*)(vtp + kk + 32 + agrp * 8);
      }
      SB();
      __builtin_amdgcn_s_barrier();   // reads done: safe to overwrite other buf
    }

    // ---- epilogue: partial slot (qT, s): 64 bf16 + t,l f32 per row ----
    const size_t pb = ((size_t)(bh * 16 + qT) * 3 + s) * 128;
#pragma unroll
    for (int r = 0; r < 4; ++r) {
      float t0 = __shfl(acc[4][r], (agrp << 4) | 0);
      float t1 = __shfl(acc[4][r], (agrp << 4) | 1);
      float ls = __shfl(acc[4][r], (agrp << 4) | 2);
      size_t rp = (pb + wave * 16 + agrp * 4 + r) * PSTRIDE;
#pragma unroll
      for (int dc = 0; dc < 4; ++dc)
        part[rp + dc * 16 + arow] = f2b(acc[dc][r]);
      if (arow == 0) {
        float* fp = (float*)(part + rp + 64);
        fp[0] = t0 + t1;
        fp[1] = ls;
      }
    }
  }
}

// ---------------------------------------------------------------------------
// Kernel 4: merge split-k partials (exact sums), mean over heads, Lorentz
// normalization. Slot validity per qT: v0: qT<=7||qT>=11; v1: qT>=6;
// v2: qT>=8 (matches attn's clamp arithmetic). Partials: bf16 A + f32 t,l.
// ---------------------------------------------------------------------------
__global__ __launch_bounds__(256) void finalize_kernel(
    const us* __restrict__ part, float* __restrict__ out)
{
  const int tid  = threadIdx.x;
  const int lane = tid & 63;
  const int gw = blockIdx.x * 4 + (tid >> 6);
  const int b = gw >> 11, si = gw & (SEQ - 1);
  const int qT = si >> 7, row = si & 127;

  const bool v0 = (qT <= 7) || (qT >= 11);
  const bool v1 = (qT >= 6);
  const bool v2 = (qT >= 8);

  float vsum = 0.f, tsum = 0.f;
#pragma unroll
  for (int h = 0; h < NH; ++h) {
    const size_t tb = ((size_t)(b * NH + h) * 16 + qT) * 3;
    float Ah = 0.f, Th = 0.f, Lh = 0.f;
    if (v0) {
      size_t rb = ((tb + 0) * 128 + row) * PSTRIDE;
      Ah += b2f(part[rb + lane]);
      const float* fp = (const float*)(part + rb + 64);
      Th += fp[0]; Lh += fp[1];
    }
    if (v1) {
      size_t rb = ((tb + 1) * 128 + row) * PSTRIDE;
      Ah += b2f(part[rb + lane]);
      const float* fp = (const float*)(part + rb + 64);
      Th += fp[0]; Lh += fp[1];
    }
    if (v2) {
      size_t rb = ((tb + 2) * 128 + row) * PSTRIDE;
      Ah += b2f(part[rb + lane]);
      const float* fp = (const float*)(part + rb + 64);
      Th += fp[0]; Lh += fp[1];
    }
    float inv = 1.0f / Lh;
    vsum = fmaf(Ah, inv, vsum);
    tsum = fmaf(Th, inv, tsum);
  }
  float ave  = vsum * 0.125f;
  float tave = tsum * 0.125f;
  float contrib = ave * ave;
  if (lane == 0) contrib -= tave * tave;
  contrib += __shfl_xor(contrib, 1);
  contrib += __shfl_xor(contrib, 2);
  contrib += __shfl_xor(contrib, 4);
  contrib += __shfl_xor(contrib, 8);
  contrib += __shfl_xor(contrib, 16);
  contrib += __shfl_xor(contrib, 32);
  float denom = sqrtf(fmaxf(fabsf(contrib), 1e-8f));
  size_t ob = ((size_t)b * SEQ + si) * (size_t)DD;
  out[ob + 1 + lane] = ave / denom;
  if (lane == 0) out[ob] = tave / denom;
}

// ---------------------------------------------------------------------------
extern "C" void kernel_launch(void* const* d_in, const int* in_sizes, int n_in,
                              void* d_out, int out_size, void* d_ws, size_t ws_size,
                              hipStream_t stream) {
  const float* Xq  = (const float*)d_in[0];
  const float* Xs  = (const float*)d_in[1];
  const float* Wq  = (const float*)d_in[2];
  const float* Bq  = (const float*)d_in[3];
  const float* Wk  = (const float*)d_in[4];
  const float* Bk  = (const float*)d_in[5];
  const float* Wv  = (const float*)d_in[6];
  const float* Bv  = (const float*)d_in[7];
  const float* scale = (const float*)d_in[8];
  float* out = (float*)d_out;

  char* p = (char*)d_ws;

  // Region 0 (30 MB): partials (28.3 MB) overlapped with W bf16 copies
  // (proj consumes Wb before attn writes part).
  us* partw = (us*)p;
  us* Wqb16 = (us*)(p + 28311552);
  us* Wkb16 = (us*)(p + 28835840);
  us* Wvb16 = (us*)(p + 29360128);
  p += 29884416;
  us* qsb = (us*)p; p += (size_t)NROW * 64 * 2;
  us* ksb = (us*)p; p += (size_t)NROW * 64 * 2;
  us* vTb = (us*)p; p += (size_t)NROW * 64 * 2;
  unsigned int* qtaw = (unsigned int*)p; p += (size_t)NROW * 4;
  unsigned int* ktaw = (unsigned int*)p; p += (size_t)NROW * 4;
  us* vtcw = (us*)p; p += (size_t)NROW * 2 * 2;

  tobf16_kernel<<<dim3(256, 3), 256, 0, stream>>>(
      Wq, Wk, Wv, Wqb16, Wkb16, Wvb16);
  proj_kernel<<<dim3(1024, 1, 3), 256, 0, stream>>>(
      Xq, Xs, Wqb16, Wkb16, Wvb16, Bq, Bk, Bv, scale,
      qsb, qtaw, ksb, ktaw, vTb, vtcw);
  attn_kernel<<<dim3(768), 512, 0, stream>>>(
      qsb, qtaw, ksb, ktaw, vTb, vtcw, partw);
  finalize_kernel<<<(BATCH * SEQ) / 4, 256, 0, stream>>>(partw, out);
}

// Round 15
// 96.387 us; speedup vs baseline: 1.0311x; 1.0311x over previous
//
#include <hip/hip_runtime.h>

// Problem constants
#define BATCH 4
#define SEQ   2048
#define INC   512
#define NH    8
#define OUTC  64      // space dim; head dim = 65
#define DD    65
#define NROW  (BATCH * NH * SEQ)   // 65536
#define PSTRIDE 72    // partial row stride in us units (144 B)

typedef float f32x4 __attribute__((ext_vector_type(4)));
typedef short short8 __attribute__((ext_vector_type(8)));
typedef short short4v __attribute__((ext_vector_type(4)));
typedef unsigned int uint2v __attribute__((ext_vector_type(2)));
typedef unsigned short us;

static __device__ __forceinline__ us f2b(float f) {
  unsigned int u = __float_as_uint(f);
  u = (u + 0x7FFFu + ((u >> 16) & 1u)) >> 16;   // RNE f32->bf16
  return (us)u;
}
static __device__ __forceinline__ float b2f(us h) {
  return __uint_as_float(((unsigned int)h) << 16);
}
static __device__ __forceinline__ unsigned int pk2(float lo, float hi) {
  unsigned int r;
  asm("v_cvt_pk_bf16_f32 %0, %1, %2" : "=v"(r) : "v"(lo), "v"(hi));
  return r;
}

#define GLDS(g, l) __builtin_amdgcn_global_load_lds( \
    (const __attribute__((address_space(1))) void*)(g), \
    (__attribute__((address_space(3))) void*)(l), 16, 0, 0)
#define SB() __builtin_amdgcn_sched_barrier(0)

// ---------------------------------------------------------------------------
// Kernel 0: f32 -> bf16 conversion for X (both) and W (all three).
// ---------------------------------------------------------------------------
__global__ __launch_bounds__(256) void tobf16_kernel(
    const float* __restrict__ Xq, const float* __restrict__ Xs,
    const float* __restrict__ Wq, const float* __restrict__ Wk,
    const float* __restrict__ Wv,
    us* __restrict__ dXq, us* __restrict__ dXs,
    us* __restrict__ dWq, us* __restrict__ dWk, us* __restrict__ dWv)
{
  const int which = blockIdx.y;
  const float* src;
  us* dst;
  int n;
  switch (which) {
    case 0: src = Xq; dst = dXq; n = BATCH * SEQ * INC; break;
    case 1: src = Xs; dst = dXs; n = BATCH * SEQ * INC; break;
    case 2: src = Wq; dst = dWq; n = NH * OUTC * INC; break;
    case 3: src = Wk; dst = dWk; n = NH * OUTC * INC; break;
    default: src = Wv; dst = dWv; n = NH * OUTC * INC; break;
  }
  for (long i = (long)blockIdx.x * 256 + threadIdx.x; i * 4 < n;
       i += (long)gridDim.x * 256) {
    f32x4 v = *(const f32x4*)(src + i * 4);
    short4v o;
    o[0] = (short)f2b(v[0]); o[1] = (short)f2b(v[1]);
    o[2] = (short)f2b(v[2]); o[3] = (short)f2b(v[3]);
    *(short4v*)(dst + i * 4) = o;
  }
}

// ---------------------------------------------------------------------------
// Kernel 1: per-head projections, GLDS double-buffered.
//   Q: space pre-scaled by al2; qta u32 = (qh|ql<<16) of al2*t.
//   K: kta u32 = (-kh)|(-kl)<<16.
//   V: TRANSPOSED in the epilogue via LDS -> writes vT [B,H,64,S] directly
//      (transpose kernel deleted); vtc bf16 planes {hi,lo} of t.
// ---------------------------------------------------------------------------
__global__ __launch_bounds__(256) void proj_kernel(
    const us* __restrict__ Xqb, const us* __restrict__ Xsb,
    const us* __restrict__ Wqb, const us* __restrict__ Wkb, const us* __restrict__ Wvb,
    const float* __restrict__ Bq, const float* __restrict__ Bk, const float* __restrict__ Bv,
    const float* __restrict__ scale_p,
    us* __restrict__ qs, unsigned int* __restrict__ qta,
    us* __restrict__ ks, unsigned int* __restrict__ kta,
    us* __restrict__ vT, us* __restrict__ vtc)
{
  const int which = blockIdx.z;
  const us* X = (which == 0) ? Xqb : Xsb;
  const us* W = (which == 0) ? Wqb : (which == 1 ? Wkb : Wvb);
  const float* Bb = (which == 0) ? Bq : (which == 1 ? Bk : Bv);
  const float al2 = (2.0f / scale_p[0]) * 1.44269504088896f;
  const float oscale = (which == 0) ? al2 : 1.0f;

  const int lin = blockIdx.x;                    // 0..1023
  const int h   = (lin >> 3) & 7;
  const int m0  = (((lin >> 6) << 3) | (lin & 7)) * 64;
  const int n0  = h * 64;

  __shared__ alignas(16) us lXf[2 * 64 * 64];
  __shared__ alignas(16) us lWf[2 * 64 * 64];

  const int tid  = threadIdx.x;
  const int lane = tid & 63;
  const int wave = tid >> 6;
  const int arow = lane & 15;
  const int agrp = lane >> 4;
  const int rl   = lane >> 3;
  const int chx  = ((lane & 7) ^ rl) * 8;
  const int r0   = wave * 8 + rl;
  const int r1   = r0 + 32;

#define PSTAGE(buf, k0) do { \
    GLDS(X + (size_t)(m0 + r0) * INC + (k0) + chx, &lXf[(buf) * 4096 + wave * 512]); \
    GLDS(X + (size_t)(m0 + r1) * INC + (k0) + chx, &lXf[(buf) * 4096 + 2048 + wave * 512]); \
    GLDS(W + (size_t)(n0 + r0) * INC + (k0) + chx, &lWf[(buf) * 4096 + wave * 512]); \
    GLDS(W + (size_t)(n0 + r1) * INC + (k0) + chx, &lWf[(buf) * 4096 + 2048 + wave * 512]); \
  } while (0)

  f32x4 acc[4] = {};
  PSTAGE(0, 0);

  for (int kk = 0; kk < 8; ++kk) {
    const int cur = kk & 1;
    if (kk < 7) {
      PSTAGE(cur ^ 1, (kk + 1) * 64);
      asm volatile("s_waitcnt vmcnt(4)");
    } else {
      asm volatile("s_waitcnt vmcnt(0)");
    }
    __builtin_amdgcn_s_barrier();
#pragma unroll
    for (int kc = 0; kc < 2; ++kc) {
      short8 af = *(const short8*)&lXf[cur * 4096 + (wave * 16 + arow) * 64 + (((kc * 4 + agrp) ^ (arow & 7)) * 8)];
#pragma unroll
      for (int c = 0; c < 4; ++c) {
        short8 bf = *(const short8*)&lWf[cur * 4096 + (c * 16 + arow) * 64 + (((kc * 4 + agrp) ^ (arow & 7)) * 8)];
        acc[c] = __builtin_amdgcn_mfma_f32_16x16x32_bf16(af, bf, acc[c], 0, 0, 0);
      }
    }
    __builtin_amdgcn_s_barrier();
  }
  // After the final barrier all waves are done reading lXf/lWf -> reusable.

  float bcol[4];
#pragma unroll
  for (int c = 0; c < 4; ++c) bcol[c] = Bb[n0 + c * 16 + arow];

  us* lT = &lXf[0];   // 64 x 72 us transpose tile (V path only)

#pragma unroll
  for (int r = 0; r < 4; ++r) {
    float s2 = 0.f;
#pragma unroll
    for (int c = 0; c < 4; ++c) {
      float v = acc[c][r] + bcol[c];
      acc[c][r] = v;
      s2 += v * v;
    }
    s2 += __shfl_xor(s2, 1); s2 += __shfl_xor(s2, 2);
    s2 += __shfl_xor(s2, 4); s2 += __shfl_xor(s2, 8);
    float tv = sqrtf(s2 + 1.0f);
    int gs = m0 + wave * 16 + agrp * 4 + r;
    int bi = gs >> 11, si = gs & (SEQ - 1);
    size_t rowbase = (size_t)(bi * NH + h) * SEQ + si;
    if (which == 2) {
      // stage bf16 V rows into LDS for the in-kernel transpose
      int lrow = wave * 16 + agrp * 4 + r;
#pragma unroll
      for (int c = 0; c < 4; ++c)
        lT[lrow * PSTRIDE + c * 16 + arow] = f2b(acc[c][r]);
      if (arow == 0) {
        us th = f2b(tv);
        us tl = f2b(tv - b2f(th));
        vtc[rowbase] = th;
        vtc[NROW + rowbase] = tl;
      }
    } else {
      us* outs = (which == 0) ? qs : ks;
      size_t obase = rowbase * 64;
#pragma unroll
      for (int c = 0; c < 4; ++c) outs[obase + c * 16 + arow] = f2b(oscale * acc[c][r]);
      if (arow == 0) {
        if (which == 0) {
          float st = al2 * tv;
          us qh = f2b(st);
          us ql = f2b(st - b2f(qh));
          qta[rowbase] = (unsigned int)qh | ((unsigned int)ql << 16);
        } else {
          kta[rowbase] = (unsigned int)(us)(f2b(tv) ^ 0x8000)
                       | ((unsigned int)(us)(f2b(tv - b2f(f2b(tv))) ^ 0x8000) << 16);
        }
      }
    }
  }

  if (which == 2) {
    __syncthreads();
    const int bi = m0 >> 11, si0 = m0 & (SEQ - 1);
    us* vbase = vT + ((size_t)(bi * NH + h) * 64) * SEQ + si0;
#pragma unroll
    for (int u0 = 0; u0 < 2; ++u0) {
      int u = tid + u0 * 256;
      int o = u >> 3, jc = u & 7;
      short8 w;
#pragma unroll
      for (int j = 0; j < 8; ++j) w[j] = (short)lT[(jc * 8 + j) * PSTRIDE + o];
      *(short8*)(vbase + (size_t)o * SEQ + jc * 8) = w;
    }
  }
}

// ---------------------------------------------------------------------------
// Kernel 3: causal flash attention (R12 structure, unchanged): 8-wave blocks
// (512 thr), QBLK=128, KBLK=64, grid 768 = 32 bh x 8 pairs {x,15-x} x 3-way
// split of the pair's 36 k-tiles. Partials 144 B/row: 64 bf16 space sums +
// t,l f32.
// ---------------------------------------------------------------------------
__global__ __launch_bounds__(512) void attn_kernel(
    const us* __restrict__ qs, const unsigned int* __restrict__ qta,
    const us* __restrict__ ks, const unsigned int* __restrict__ kta,
    const us* __restrict__ vT, const us* __restrict__ vtc,
    us* __restrict__ part)
{
  // XCD-aware swizzle: the 24 blocks of one bh land on one XCD.
  const int f = blockIdx.x;              // 768 blocks
  const int xcd = f & 7, idx = f >> 3;   // idx in [0,96)
  const int bh = xcd * 4 + (idx / 24);
  const int inner = idx % 24;
  const int x = inner / 3;               // pair {x, 15-x}
  const int s = inner % 3;               // 3-way split slot
  const int n0 = 2 * x + 2;
  const int n1 = 32 - 2 * x;

  __shared__ alignas(16) us lK[2][64 * 64];
  __shared__ alignas(16) us lV[2][64 * 64];
  __shared__ alignas(16) us lP[8][16 * 40];

  const int tid  = threadIdx.x;
  const int lane = tid & 63;
  const int wave = tid >> 6;     // 0..7
  const int arow = lane & 15;
  const int agrp = lane >> 4;

  const size_t bhbase = (size_t)bh * SEQ;
  const us* kgp = ks + bhbase * 64;
  const us* vgp = vT + (size_t)bh * 64 * SEQ;
  const unsigned int* ktp = kta + bhbase;
  const us* vtp = vtc + (size_t)(arow & 1) * NROW + bhbase;

  const int rl   = lane >> 3;
  const int chx  = ((lane & 7) ^ rl) * 8;
  const int dsl0 = (agrp ^ (arow & 7)) * 8;
  const int dsl1 = ((4 + agrp) ^ (arow & 7)) * 8;
  us* myP = &lP[wave][0];
  const int pw0 = arow * 40 + agrp * 4;   // P b64 write (c=1: +16)
  const int prd = arow * 40 + agrp * 8;   // pf b128 read

#define ASTAGE(buf, t64) do { \
    const int kk = (t64) * 64; \
    GLDS(kgp + (size_t)(kk + wave * 8 + rl) * 64 + chx, &lK[buf][wave * 512]); \
    GLDS(vgp + (size_t)(wave * 8 + rl) * SEQ + kk + chx, &lV[buf][wave * 512]); \
  } while (0)

  short8 ones8, zero8 = {};
#pragma unroll
  for (int j = 0; j < 8; ++j) ones8[j] = (short)0x3F80;

  for (int seg = 0; seg < 2; ++seg) {
    const int qT = seg ? (15 - x) : x;
    int lo, hi;
    if (seg == 0) { lo = min(12 * s, n0);          hi = min(12 * s + 12, n0); }
    else          { lo = max(12 * s - n0, 0);      hi = min(12 * s + 12 - n0, n1); }
    const int nt = hi - lo;
    if (nt <= 0) continue;

    const int wq = qT * 128 + wave * 16 + arow;
    f32x4 acc[5] = {};

    // Q fragments + time terms (3 VMEM)
    const us* qp = qs + (bhbase + wq) * 64;
    short8 qf0 = *(const short8*)(qp + agrp * 8);
    short8 qf1 = *(const short8*)(qp + 32 + agrp * 8);
    unsigned int qw = qta[bhbase + wq];
    short8 qf2 = {};
    if (agrp == 0) {
      qf2[0] = (short)(qw & 0xFFFFu);
      qf2[1] = (short)(qw & 0xFFFFu);
      qf2[2] = (short)(qw >> 16);
    }

    // aug regs for first tile (4 + 2 = 6 VMEM)
    unsigned int ka[4];
    short8 va0, va1;
    {
      const int kk = lo * 64;
#pragma unroll
      for (int c = 0; c < 4; ++c) ka[c] = ktp[kk + c * 16 + arow];
      va0 = *(const short8*)(vtp + kk + agrp * 8);
      va1 = *(const short8*)(vtp + kk + 32 + agrp * 8);
    }
    SB();
    ASTAGE(0, lo);
    SB();

    for (int it = 0; it < nt; ++it) {
      const int t = lo + it;
      const int cur = it & 1;
      if (it < nt - 1) {
        ASTAGE(cur ^ 1, t + 1);
        SB();
        asm volatile("s_waitcnt vmcnt(2)");
      } else {
        SB();
        asm volatile("s_waitcnt vmcnt(0)");
      }
      SB();
      __builtin_amdgcn_s_barrier();

      const us* Kb = lK[cur];
      const us* Vb = lV[cur];

      // ---- S^T = K' Q'^T (augmented: includes -qt*kt hi/lo) ----
      f32x4 sS[4] = {};
      __builtin_amdgcn_s_setprio(1);
#pragma unroll
      for (int c = 0; c < 4; ++c) {
        short8 kf = *(const short8*)&Kb[(c * 16 + arow) * 64 + dsl0];
        sS[c] = __builtin_amdgcn_mfma_f32_16x16x32_bf16(kf, qf0, sS[c], 0, 0, 0);
      }
#pragma unroll
      for (int c = 0; c < 4; ++c) {
        short8 kf = *(const short8*)&Kb[(c * 16 + arow) * 64 + dsl1];
        sS[c] = __builtin_amdgcn_mfma_f32_16x16x32_bf16(kf, qf1, sS[c], 0, 0, 0);
      }
#pragma unroll
      for (int c = 0; c < 4; ++c) {
        short8 kf2 = {};
        if (agrp == 0) {
          unsigned int w0 = ka[c];
          kf2[0] = (short)(w0 & 0xFFFFu);
          kf2[1] = (short)(w0 >> 16);
          kf2[2] = (short)(w0 & 0xFFFFu);
        }
        sS[c] = __builtin_amdgcn_mfma_f32_16x16x32_bf16(kf2, qf2, sS[c], 0, 0, 0);
      }
      __builtin_amdgcn_s_setprio(0);

      // ---- P = exp2(logit) (Q pre-scaled); causal mask -> exact 0 ----
#pragma unroll
      for (int c = 0; c < 4; ++c)
#pragma unroll
        for (int r = 0; r < 4; ++r)
          sS[c][r] = exp2f(sS[c][r]);
      if (t >= 2 * qT) {     // the two diagonal-straddling k-tiles
        const int kb = t * 64;
#pragma unroll
        for (int c = 0; c < 4; ++c)
#pragma unroll
          for (int r = 0; r < 4; ++r)
            if (kb + c * 16 + agrp * 4 + r > wq) sS[c][r] = 0.f;
      }

      // ---- PV: 2 phases over kc, wave-private 1.25KB P tile reused ----
      {
        uint2v w;
        w[0] = pk2(sS[0][0], sS[0][1]); w[1] = pk2(sS[0][2], sS[0][3]);
        *(uint2v*)&myP[pw0] = w;
        w[0] = pk2(sS[1][0], sS[1][1]); w[1] = pk2(sS[1][2], sS[1][3]);
        *(uint2v*)&myP[pw0 + 16] = w;
        short8 pf = *(const short8*)&myP[prd];
        __builtin_amdgcn_s_setprio(1);
#pragma unroll
        for (int dc = 0; dc < 4; ++dc) {
          short8 vf = *(const short8*)&Vb[(dc * 16 + arow) * 64 + dsl0];
          acc[dc] = __builtin_amdgcn_mfma_f32_16x16x32_bf16(pf, vf, acc[dc], 0, 0, 0);
        }
        short8 vf4 = (arow < 2) ? va0 : ((arow == 2) ? ones8 : zero8);
        acc[4] = __builtin_amdgcn_mfma_f32_16x16x32_bf16(pf, vf4, acc[4], 0, 0, 0);
        __builtin_amdgcn_s_setprio(0);
      }
      {
        uint2v w;
        w[0] = pk2(sS[2][0], sS[2][1]); w[1] = pk2(sS[2][2], sS[2][3]);
        *(uint2v*)&myP[pw0] = w;
        w[0] = pk2(sS[3][0], sS[3][1]); w[1] = pk2(sS[3][2], sS[3][3]);
        *(uint2v*)&myP[pw0 + 16] = w;
        short8 pf = *(const short8*)&myP[prd];
        __builtin_amdgcn_s_setprio(1);
#pragma unroll
        for (int dc = 0; dc < 4; ++dc) {
          short8 vf = *(const short8*)&Vb[(dc * 16 + arow) * 64 + dsl1];
          acc[dc] = __builtin_amdgcn_mfma_f32_16x16x32_bf16(pf, vf, acc[dc], 0, 0, 0);
        }
        short8 vf4 = (arow < 2) ? va1 : ((arow == 2) ? ones8 : zero8);
        acc[4] = __builtin_amdgcn_mfma_f32_16x16x32_bf16(pf, vf4, acc[4], 0, 0, 0);
        __builtin_amdgcn_s_setprio(0);
      }

      // aug prefetch for next tile (in flight across the barrier)
      SB();
      if (it + 1 < nt) {
        const int kk = (t + 1) * 64;
#pragma unroll
        for (int c = 0; c < 4; ++c) ka[c] = ktp[kk + c * 16 + arow];
        va0 = *(const short8*)(vtp + kk + agrp * 8);
        va1 = *(const short8*)(vtp + kk + 32 + agrp * 8);
      }
      SB();
      __builtin_amdgcn_s_barrier();   // reads done: safe to overwrite other buf
    }

    // ---- epilogue: partial slot (qT, s): 64 bf16 + t,l f32 per row ----
    const size_t pb = ((size_t)(bh * 16 + qT) * 3 + s) * 128;
#pragma unroll
    for (int r = 0; r < 4; ++r) {
      float t0 = __shfl(acc[4][r], (agrp << 4) | 0);
      float t1 = __shfl(acc[4][r], (agrp << 4) | 1);
      float ls = __shfl(acc[4][r], (agrp << 4) | 2);
      size_t rp = (pb + wave * 16 + agrp * 4 + r) * PSTRIDE;
#pragma unroll
      for (int dc = 0; dc < 4; ++dc)
        part[rp + dc * 16 + arow] = f2b(acc[dc][r]);
      if (arow == 0) {
        float* fp = (float*)(part + rp + 64);
        fp[0] = t0 + t1;
        fp[1] = ls;
      }
    }
  }
}

// ---------------------------------------------------------------------------
// Kernel 4: merge split-k partials (exact sums), mean over heads, Lorentz
// normalization. Slot validity per qT: v0: qT<=7||qT>=11; v1: qT>=6;
// v2: qT>=8 (matches attn's clamp arithmetic). Partials: bf16 A + f32 t,l.
// ---------------------------------------------------------------------------
__global__ __launch_bounds__(256) void finalize_kernel(
    const us* __restrict__ part, float* __restrict__ out)
{
  const int tid  = threadIdx.x;
  const int lane = tid & 63;
  const int gw = blockIdx.x * 4 + (tid >> 6);
  const int b = gw >> 11, si = gw & (SEQ - 1);
  const int qT = si >> 7, row = si & 127;

  const bool v0 = (qT <= 7) || (qT >= 11);
  const bool v1 = (qT >= 6);
  const bool v2 = (qT >= 8);

  float vsum = 0.f, tsum = 0.f;
#pragma unroll
  for (int h = 0; h < NH; ++h) {
    const size_t tb = ((size_t)(b * NH + h) * 16 + qT) * 3;
    float Ah = 0.f, Th = 0.f, Lh = 0.f;
    if (v0) {
      size_t rb = ((tb + 0) * 128 + row) * PSTRIDE;
      Ah += b2f(part[rb + lane]);
      const float* fp = (const float*)(part + rb + 64);
      Th += fp[0]; Lh += fp[1];
    }
    if (v1) {
      size_t rb = ((tb + 1) * 128 + row) * PSTRIDE;
      Ah += b2f(part[rb + lane]);
      const float* fp = (const float*)(part + rb + 64);
      Th += fp[0]; Lh += fp[1];
    }
    if (v2) {
      size_t rb = ((tb + 2) * 128 + row) * PSTRIDE;
      Ah += b2f(part[rb + lane]);
      const float* fp = (const float*)(part + rb + 64);
      Th += fp[0]; Lh += fp[1];
    }
    float inv = 1.0f / Lh;
    vsum = fmaf(Ah, inv, vsum);
    tsum = fmaf(Th, inv, tsum);
  }
  float ave  = vsum * 0.125f;
  float tave = tsum * 0.125f;
  float contrib = ave * ave;
  if (lane == 0) contrib -= tave * tave;
  contrib += __shfl_xor(contrib, 1);
  contrib += __shfl_xor(contrib, 2);
  contrib += __shfl_xor(contrib, 4);
  contrib += __shfl_xor(contrib, 8);
  contrib += __shfl_xor(contrib, 16);
  contrib += __shfl_xor(contrib, 32);
  float denom = sqrtf(fmaxf(fabsf(contrib), 1e-8f));
  size_t ob = ((size_t)b * SEQ + si) * (size_t)DD;
  out[ob + 1 + lane] = ave / denom;
  if (lane == 0) out[ob] = tave / denom;
}

// ---------------------------------------------------------------------------
extern "C" void kernel_launch(void* const* d_in, const int* in_sizes, int n_in,
                              void* d_out, int out_size, void* d_ws, size_t ws_size,
                              hipStream_t stream) {
  const float* Xq  = (const float*)d_in[0];
  const float* Xs  = (const float*)d_in[1];
  const float* Wq  = (const float*)d_in[2];
  const float* Bq  = (const float*)d_in[3];
  const float* Wk  = (const float*)d_in[4];
  const float* Bk  = (const float*)d_in[5];
  const float* Wv  = (const float*)d_in[6];
  const float* Bv  = (const float*)d_in[7];
  const float* scale = (const float*)d_in[8];
  float* out = (float*)d_out;

  char* p = (char*)d_ws;

  // Region 0 (35.7 MB): partials (28.3 MB) overlapped with bf16 X and W
  // copies (proj consumes Xb/Wb before attn writes part).
  us* partw = (us*)p;
  us* Xqb   = (us*)p;
  us* Xsb   = (us*)(p + 16777216);
  us* Wqb16 = (us*)(p + 33554432);
  us* Wkb16 = (us*)(p + 34078720);
  us* Wvb16 = (us*)(p + 34603008);
  p += 35651584;
  us* qsb = (us*)p; p += (size_t)NROW * 64 * 2;
  us* ksb = (us*)p; p += (size_t)NROW * 64 * 2;
  us* vTb = (us*)p; p += (size_t)NROW * 64 * 2;
  unsigned int* qtaw = (unsigned int*)p; p += (size_t)NROW * 4;
  unsigned int* ktaw = (unsigned int*)p; p += (size_t)NROW * 4;
  us* vtcw = (us*)p; p += (size_t)NROW * 2 * 2;

  tobf16_kernel<<<dim3(1024, 5), 256, 0, stream>>>(
      Xq, Xs, Wq, Wk, Wv, Xqb, Xsb, Wqb16, Wkb16, Wvb16);
  proj_kernel<<<dim3(1024, 1, 3), 256, 0, stream>>>(
      Xqb, Xsb, Wqb16, Wkb16, Wvb16, Bq, Bk, Bv, scale,
      qsb, qtaw, ksb, ktaw, vTb, vtcw);
  attn_kernel<<<dim3(768), 512, 0, stream>>>(
      qsb, qtaw, ksb, ktaw, vTb, vtcw, partw);
  finalize_kernel<<<(BATCH * SEQ) / 4, 256, 0, stream>>>(partw, out);
}